// Round 12
// baseline (1026.214 us; speedup 1.0000x reference)
//
#include <hip/hip_runtime.h>
#include <hip/hip_bf16.h>
#include <stdint.h>

// Problem constants
#define NB 64      // batch
#define NT 128     // seq len
#define NE 512     // embed
#define NH 1024    // hidden
#define NV 32000   // vocab
#define NM (NB*NT) // 8192 flattened (t-major: m = t*64 + b)

// Kernel config: 2 independent batch-groups of 128 wgs. Group g = wg>>7 owns
// batches [32g, 32g+32); each wg computes 8 hidden units x 32 batches.
#define NWG 256
#define NTH 512
#define WPG 128            // wgs per group
#define FLAG_STRIDE 32u    // one flag per 128-B LLC line

// History half-slots per group, write-once, FRAGMENT-MAJOR:
// shorts offset (rb,kk,lane,j) = ((rb*32+kk)*64+lane)*8+j holds
// h[g*32 + rb*16 + (lane&15)][kk*32 + (lane>>4)*8 + j].
#define HS_SHORTS 32768u                        // 64 KB half-slot
#define GSTRIDE_SH (129u*HS_SHORTS)             // shorts per group hist
#define WS_FLAGS_S 0u                           // 32 KB: startup flags (256 lines)
#define WS_FLAGS_G 32768u                       // 32 KB: per-group arrival flags
#define WS_EPOCH   65536u                       // 4 KB: 2 epoch lines (aggregated barrier)
#define WS_H0      131072u
#define WS_H1      (WS_H0 + 2u*129u*65536u)     // +16,908,288
#define WS_CNT     (WS_H1 + 2u*129u*65536u)
#define WS_XS0     (WS_CNT + 4u*NB*NV)
#define WS_NEEDED  (WS_XS0 + 2u*NM*NE)

typedef __attribute__((ext_vector_type(8))) short bf16x8;
typedef __attribute__((ext_vector_type(4))) float f32x4;

#define SCOPE_AG  __HIP_MEMORY_SCOPE_AGENT

__device__ __forceinline__ unsigned short f2bf(float f) {
  unsigned u = __float_as_uint(f);
  u += 0x7FFFu + ((u >> 16) & 1u);   // round-nearest-even
  return (unsigned short)(u >> 16);
}
__device__ __forceinline__ float sigmoidf_(float x) {
  return 1.0f / (1.0f + expf(-x));
}
__device__ __forceinline__ bf16x8 pack8(float4 a, float4 b) {
  bf16x8 v;
  v[0]=(short)f2bf(a.x); v[1]=(short)f2bf(a.y); v[2]=(short)f2bf(a.z); v[3]=(short)f2bf(a.w);
  v[4]=(short)f2bf(b.x); v[5]=(short)f2bf(b.y); v[6]=(short)f2bf(b.z); v[7]=(short)f2bf(b.w);
  return v;
}

#define MFMA(a,b,c) __builtin_amdgcn_mfma_f32_16x16x32_bf16((a),(b),(c),0,0,0)

__global__ void __launch_bounds__(NTH, 2)
lstm_all(const int* __restrict__ x, const float* __restrict__ emb,
         const float* __restrict__ w_ih0, const float* __restrict__ w_hh0,
         const float* __restrict__ b_ih0, const float* __restrict__ b_hh0,
         const float* __restrict__ w_ih1, const float* __restrict__ w_hh1,
         const float* __restrict__ b_ih1, const float* __restrict__ b_hh1,
         const float* __restrict__ fc_w, const float* __restrict__ fc_b,
         float* __restrict__ out, unsigned char* __restrict__ wsb)
{
  // LDS ~145 KB: weight slices in MFMA-fragment order [(ct)][kk][lane][8]
  __shared__ unsigned short sWih1[2*32*64*8];   // 64 KB: w_ih1 ct0+ct1
  __shared__ unsigned short sWhh0c1[32*64*8];   // 32 KB: w_hh0 ct1
  __shared__ unsigned short sWhh1c1[32*64*8];   // 32 KB: w_hh1 ct1
  __shared__ float sG0[32][32], sG1a[32][32], sG1b[32][32], sGih[32][32];
  __shared__ float sB0[32], sB1[32];
  __shared__ alignas(16) unsigned short sH0[32][8], sH1[32][8];

  const int wg  = blockIdx.x;
  const int tid = threadIdx.x;
  const int wave = tid >> 6, lane = tid & 63;
  const int lr = lane & 15, lq = lane >> 4;
  const int g  = wg >> 7;          // batch group
  const int wgl = wg & 127;        // wg within group (unit base = wgl*8)

  unsigned* flagsS = (unsigned*)(wsb + WS_FLAGS_S);
  unsigned* gf     = (unsigned*)(wsb + WS_FLAGS_G) + (unsigned)g*WPG*FLAG_STRIDE;
  unsigned* epoch  = (unsigned*)(wsb + WS_EPOCH) + (unsigned)g*FLAG_STRIDE;
  unsigned short* h0g = (unsigned short*)(wsb + WS_H0) + (size_t)g*GSTRIDE_SH;
  unsigned short* h1g = (unsigned short*)(wsb + WS_H1) + (size_t)g*GSTRIDE_SH;
  unsigned* counts = (unsigned*)(wsb + WS_CNT);
  unsigned short* xs0 = (unsigned short*)(wsb + WS_XS0);

  // ---- breg: step-invariant B-fragments (ct0 of the wave's weight matrix) ----
  // w2/w3: w_hh0 ct0; w0/w1: w_hh1 ct0; w4/w5: w_ih0 ct0(kk<16)+ct1(kk>=16).
  bf16x8 breg[32];
  {
    const int ggr0 = (lr >> 3)*NH + wgl*8 + (lr & 7);          // col c = lr
    const int ggr1 = (2 + (lr >> 3))*NH + wgl*8 + (lr & 7);    // col c = 16+lr
    if (wave == 2 || wave == 3) {
      const float* src = w_hh0 + (size_t)ggr0*NH + lq*8;
      #pragma unroll
      for (int kk = 0; kk < 32; ++kk)
        breg[kk] = pack8(*(const float4*)(src + kk*32), *(const float4*)(src + kk*32 + 4));
    } else if (wave == 0 || wave == 1) {
      const float* src = w_hh1 + (size_t)ggr0*NH + lq*8;
      #pragma unroll
      for (int kk = 0; kk < 32; ++kk)
        breg[kk] = pack8(*(const float4*)(src + kk*32), *(const float4*)(src + kk*32 + 4));
    } else if (wave == 4 || wave == 5) {
      const float* s0 = w_ih0 + (size_t)ggr0*NE + lq*8;
      const float* s1 = w_ih0 + (size_t)ggr1*NE + lq*8;
      #pragma unroll
      for (int kk = 0; kk < 16; ++kk) {
        breg[kk]    = pack8(*(const float4*)(s0 + kk*32), *(const float4*)(s0 + kk*32 + 4));
        breg[16+kk] = pack8(*(const float4*)(s1 + kk*32), *(const float4*)(s1 + kk*32 + 4));
      }
    }
  }

  // ---- gather embeddings -> xs0 (bf16, per-group fragment-major), sc1 ----
  for (int i = wg*NTH + tid; i < NM*(NE/8); i += NWG*NTH) {
    int m = i >> 6;
    int e8 = (i & 63) << 3;
    int t = m >> 6, b = m & 63;
    int tok = x[b*NT + t];
    const float* s = emb + (size_t)tok*NE + e8;
    union { bf16x8 v8; unsigned long long u[2]; } u;
    u.v8 = pack8(*(const float4*)s, *(const float4*)(s + 4));
    int gg = b >> 5, bb = b & 31;
    size_t off = ((size_t)((gg*NT + t)*2 + (bb >> 4)))*8192
               + ((size_t)((e8 >> 5)*64 + ((e8 >> 3) & 3)*16 + (bb & 15)))*8;
    unsigned long long* dst = (unsigned long long*)(xs0 + off);
    __hip_atomic_store(dst,   u.u[0], __ATOMIC_RELAXED, SCOPE_AG);
    __hip_atomic_store(dst+1, u.u[1], __ATOMIC_RELAXED, SCOPE_AG);
  }

  // ---- weight slices -> LDS in fragment order ----
  for (int i = tid; i < 2*32*64; i += NTH) {        // sWih1 ct0+ct1
    int ct = i >> 11, kk = (i >> 6) & 31, l = i & 63;
    int glr = l & 15, glq = l >> 4;
    int c = ct*16 + glr;
    int ggr = (c >> 3)*NH + wgl*8 + (c & 7);
    const float* p = w_ih1 + (size_t)ggr*NH + kk*32 + glq*8;
    ((bf16x8*)sWih1)[i] = pack8(*(const float4*)p, *(const float4*)(p + 4));
  }
  for (int i = tid; i < 32*64; i += NTH) {          // sWhh0c1 / sWhh1c1
    int kk = i >> 6, l = i & 63;
    int glr = l & 15, glq = l >> 4;
    int ggr = (2 + (glr >> 3))*NH + wgl*8 + (glr & 7);   // col c = 16+glr
    const float* p0 = w_hh0 + (size_t)ggr*NH + kk*32 + glq*8;
    const float* p1 = w_hh1 + (size_t)ggr*NH + kk*32 + glq*8;
    ((bf16x8*)sWhh0c1)[i] = pack8(*(const float4*)p0, *(const float4*)(p0 + 4));
    ((bf16x8*)sWhh1c1)[i] = pack8(*(const float4*)p1, *(const float4*)(p1 + 4));
  }
  if (tid < 32) {
    int g2 = (tid >> 3)*NH + wgl*8 + (tid & 7);
    sB0[tid] = b_ih0[g2] + b_hh0[g2];
    sB1[tid] = b_ih1[g2] + b_hh1[g2];
  }
  // ---- token histogram ----
  {
    int i = wg*NTH + tid;
    if (i < NB*NT) {
      int b = i >> 7;
      atomicAdd(&counts[(size_t)b*NV + x[i]], 1u);
    }
  }
  // ---- startup: GLOBAL barrier (gather written by all wgs) ----
  __syncthreads();
  if (tid == 0)
    __hip_atomic_store(&flagsS[(unsigned)wg * FLAG_STRIDE], 1u, __ATOMIC_RELAXED, SCOPE_AG);
  if (tid < NWG) {
    while (__hip_atomic_load(&flagsS[(unsigned)tid * FLAG_STRIDE], __ATOMIC_RELAXED, SCOPE_AG) < 1u)
      __builtin_amdgcn_s_sleep(8);
  }
  __syncthreads();

  // ---- scan: 129 steps, per-group aggregated barrier ----
  // w2/w3 (rb=w-2): A=hist0[t] -> a0ct0(breg) a0ct1(LDS) a1ct0 a1ct1(LDS)
  // w0/w1 (rb=w):   A=hist1[t-1] -> a2ct0(breg) a2ct1(LDS)
  // w4/w5 (rb=w-4): A=xs[t] -> ai ct0/ct1 (breg)
  // cells tid<256: layer0 t; tid>=256: layer1 t-1. w6/w7 publish.
  float c_reg = 0.f;
  const int cbb = (tid & 255) >> 3, cu8 = tid & 7;
  for (int t = 0; t <= NT; ++t) {
    if (wave == 2 || wave == 3) {
      const int rb = wave - 2;
      const unsigned short* A = h0g + (size_t)t*HS_SHORTS + rb*16384 + lane*8;
      f32x4 a00 = {0.f,0.f,0.f,0.f}, a01 = {0.f,0.f,0.f,0.f};
      f32x4 a10 = {0.f,0.f,0.f,0.f}, a11 = {0.f,0.f,0.f,0.f};
      #pragma unroll
      for (int kk = 0; kk < 32; ++kk) {
        bf16x8 af = *(const bf16x8*)(A + kk*512);
        a00 = MFMA(af, breg[kk], a00);
        a01 = MFMA(af, ((const bf16x8*)sWhh0c1)[kk*64 + lane], a01);
        a10 = MFMA(af, ((const bf16x8*)sWih1)[kk*64 + lane], a10);
        a11 = MFMA(af, ((const bf16x8*)sWih1)[(32+kk)*64 + lane], a11);
      }
      #pragma unroll
      for (int r = 0; r < 4; ++r) {
        int row = rb*16 + lq*4 + r;
        sG0 [row][lr]    = a00[r];
        sG0 [row][16+lr] = a01[r];
        sG1a[row][lr]    = a10[r];
        sG1a[row][16+lr] = a11[r];
      }
    } else if (wave == 0 || wave == 1) {
      if (t >= 1) {
        const int rb = wave;
        const unsigned short* A = h1g + (size_t)(t-1)*HS_SHORTS + rb*16384 + lane*8;
        f32x4 a20 = {0.f,0.f,0.f,0.f}, a21 = {0.f,0.f,0.f,0.f};
        #pragma unroll
        for (int kk = 0; kk < 32; ++kk) {
          bf16x8 af = *(const bf16x8*)(A + kk*512);
          a20 = MFMA(af, breg[kk], a20);
          a21 = MFMA(af, ((const bf16x8*)sWhh1c1)[kk*64 + lane], a21);
        }
        #pragma unroll
        for (int r = 0; r < 4; ++r) {
          int row = rb*16 + lq*4 + r;
          sG1b[row][lr]    = a20[r];
          sG1b[row][16+lr] = a21[r];
        }
      }
    } else if (wave == 4 || wave == 5) {
      if (t < NT) {
        const int rb = wave - 4;
        const unsigned short* A = xs0 + ((size_t)((g*NT + t)*2 + rb))*8192 + lane*8;
        f32x4 ai0 = {0.f,0.f,0.f,0.f}, ai1 = {0.f,0.f,0.f,0.f};
        #pragma unroll
        for (int kk = 0; kk < 16; ++kk) {
          bf16x8 af = *(const bf16x8*)(A + kk*512);
          ai0 = MFMA(af, breg[kk], ai0);
          ai1 = MFMA(af, breg[16+kk], ai1);
        }
        #pragma unroll
        for (int r = 0; r < 4; ++r) {
          int row = rb*16 + lq*4 + r;
          sGih[row][lr]    = ai0[r];
          sGih[row][16+lr] = ai1[r];
        }
      }
    }
    __syncthreads();
    // ---- cells ----
    if (tid < 256) {
      if (t < NT) {
        float gi = sG0[cbb][cu8]    + sGih[cbb][cu8]    + sB0[cu8];
        float gf = sG0[cbb][8+cu8]  + sGih[cbb][8+cu8]  + sB0[8+cu8];
        float gg = sG0[cbb][16+cu8] + sGih[cbb][16+cu8] + sB0[16+cu8];
        float go = sG0[cbb][24+cu8] + sGih[cbb][24+cu8] + sB0[24+cu8];
        float ii = sigmoidf_(gi), ff = sigmoidf_(gf), gv = tanhf(gg), oo = sigmoidf_(go);
        c_reg = ff*c_reg + ii*gv;
        sH0[cbb][cu8] = f2bf(oo * tanhf(c_reg));
      }
    } else {
      if (t >= 1) {
        float gi = sG1a[cbb][cu8]    + sG1b[cbb][cu8]    + sB1[cu8];
        float gf = sG1a[cbb][8+cu8]  + sG1b[cbb][8+cu8]  + sB1[8+cu8];
        float gg = sG1a[cbb][16+cu8] + sG1b[cbb][16+cu8] + sB1[16+cu8];
        float go = sG1a[cbb][24+cu8] + sG1b[cbb][24+cu8] + sB1[24+cu8];
        float ii = sigmoidf_(gi), ff = sigmoidf_(gf), gv = tanhf(gg), oo = sigmoidf_(go);
        c_reg = ff*c_reg + ii*gv;
        sH1[cbb][cu8] = f2bf(oo * tanhf(c_reg));
      }
    }
    __syncthreads();
    // ---- publish (w6: hist0 slot t+1, w7: hist1 slot t), 8 B sc1/lane ----
    if (wave == 6 && t < NT) {
      int bb = lane >> 1, j0 = (lane & 1)*4;
      unsigned long long v = *(const unsigned long long*)&sH0[bb][j0];
      size_t off = ((size_t)(((bb >> 4)*32 + (wgl >> 2))*64 + (wgl & 3)*16 + (bb & 15)))*8 + j0;
      __hip_atomic_store((unsigned long long*)(h0g + (size_t)(t+1)*HS_SHORTS + off),
                         v, __ATOMIC_RELAXED, SCOPE_AG);
    }
    if (wave == 7 && t >= 1) {
      int bb = lane >> 1, j0 = (lane & 1)*4;
      unsigned long long v = *(const unsigned long long*)&sH1[bb][j0];
      size_t off = ((size_t)(((bb >> 4)*32 + (wgl >> 2))*64 + (wgl & 3)*16 + (bb & 15)))*8 + j0;
      __hip_atomic_store((unsigned long long*)(h1g + (size_t)t*HS_SHORTS + off),
                         v, __ATOMIC_RELAXED, SCOPE_AG);
    }
    // ---- per-group barrier: arrival flags -> aggregator -> epoch broadcast ----
    __syncthreads();   // drains vmcnt: publishes LLC-visible before arrival flag
    if (tid == 0)
      __hip_atomic_store(&gf[(unsigned)wgl * FLAG_STRIDE], (unsigned)(t+1),
                         __ATOMIC_RELAXED, SCOPE_AG);
    if (wave == 0) {
      const unsigned need = (unsigned)(t+1);
      if (wgl == 0) {
        // aggregator: one wave polls all 128 group flags (2 per lane)
        for (;;) {
          unsigned f0 = __hip_atomic_load(&gf[(unsigned)lane * FLAG_STRIDE],
                                          __ATOMIC_RELAXED, SCOPE_AG);
          unsigned f1 = __hip_atomic_load(&gf[(unsigned)(lane + 64) * FLAG_STRIDE],
                                          __ATOMIC_RELAXED, SCOPE_AG);
          if (__all(f0 >= need && f1 >= need)) break;
          __builtin_amdgcn_s_sleep(1);
        }
        if (lane == 0)
          __hip_atomic_store(epoch, need, __ATOMIC_RELAXED, SCOPE_AG);
      } else {
        // consumers: all 64 lanes poll the SAME epoch line (1 line access/iter)
        while (__hip_atomic_load(epoch, __ATOMIC_RELAXED, SCOPE_AG) < need)
          __builtin_amdgcn_s_sleep(1);
      }
    }
    __syncthreads();
  }

  // ---- FC + repetition penalty (group's h1[127] = hist1 slot 128) ----
  {
    const unsigned short* ab = h1g + (size_t)128*HS_SHORTS + lane*8;
    for (int tile = wgl*8 + wave; tile < NV/16; tile += WPG*8) {
      int c0 = tile*16;
      const float* wb = fc_w + (size_t)(c0 + lr)*NH + lq*8;
      f32x4 acc0 = {0.f,0.f,0.f,0.f}, acc1 = {0.f,0.f,0.f,0.f};
      #pragma unroll 4
      for (int kk = 0; kk < 32; ++kk) {
        bf16x8 bfv = pack8(*(const float4*)(wb + kk*32), *(const float4*)(wb + kk*32 + 4));
        acc0 = MFMA(*(const bf16x8*)(ab + kk*512),         bfv, acc0);
        acc1 = MFMA(*(const bf16x8*)(ab + 16384 + kk*512), bfv, acc1);
      }
      int c = c0 + lr;
      float fb = fc_b[c];
      #pragma unroll
      for (int r = 0; r < 4; ++r) {
        int b0 = g*32 + lq*4 + r;          // rb = 0
        int b1 = b0 + 16;                  // rb = 1
        unsigned cnt0 = counts[(size_t)b0*NV + c];
        unsigned cnt1 = counts[(size_t)b1*NV + c];
        out[(size_t)b0*NV + c] = (acc0[r] + fb) * exp2f(-0.26303440583379378f * (float)cnt0);
        out[(size_t)b1*NV + c] = (acc1[r] + fb) * exp2f(-0.26303440583379378f * (float)cnt1);
      }
    }
  }
}

extern "C" void kernel_launch(void* const* d_in, const int* in_sizes, int n_in,
                              void* d_out, int out_size, void* d_ws, size_t ws_size,
                              hipStream_t stream) {
  const int*   x     = (const int*)  d_in[0];
  const float* emb   = (const float*)d_in[1];
  const float* w_ih0 = (const float*)d_in[2];
  const float* w_hh0 = (const float*)d_in[3];
  const float* b_ih0 = (const float*)d_in[4];
  const float* b_hh0 = (const float*)d_in[5];
  const float* w_ih1 = (const float*)d_in[6];
  const float* w_hh1 = (const float*)d_in[7];
  const float* b_ih1 = (const float*)d_in[8];
  const float* b_hh1 = (const float*)d_in[9];
  const float* fc_w  = (const float*)d_in[10];
  const float* fc_b  = (const float*)d_in[11];
  if (ws_size < WS_NEEDED) return;
  unsigned char* ws = (unsigned char*)d_ws;
  (void)hipMemsetAsync(ws, 0, WS_H0, stream);                          // flags + epoch
  (void)hipMemsetAsync(ws + WS_H0, 0, 65536, stream);                  // hist0 g0 slot 0
  (void)hipMemsetAsync(ws + WS_H0 + 129u*65536u, 0, 65536, stream);    // hist0 g1 slot 0
  (void)hipMemsetAsync(ws + WS_H1, 0, 65536, stream);                  // hist1 g0 slot 0
  (void)hipMemsetAsync(ws + WS_H1 + 129u*65536u, 0, 65536, stream);    // hist1 g1 slot 0
  (void)hipMemsetAsync(ws + WS_CNT, 0, 4u*NB*NV, stream);              // token histogram
  hipLaunchKernelGGL(lstm_all, dim3(NWG), dim3(NTH), 0, stream,
                     x, emb, w_ih0, w_hh0, b_ih0, b_hh0,
                     w_ih1, w_hh1, b_ih1, b_hh1, fc_w, fc_b,
                     (float*)d_out, (unsigned char*)d_ws);
}

// Round 13
// 999.681 us; speedup vs baseline: 1.0265x; 1.0265x over previous
//
#include <hip/hip_runtime.h>
#include <hip/hip_bf16.h>
#include <stdint.h>

// Problem constants
#define NB 64      // batch
#define NT 128     // seq len
#define NE 512     // embed
#define NH 1024    // hidden
#define NV 32000   // vocab
#define NM (NB*NT) // 8192 flattened (t-major: m = t*64 + b)

// Kernel config: 2 independent batch-groups of 128 wgs. Group g = wg>>7 owns
// batches [32g, 32g+32); each wg computes 8 hidden units x 32 batches.
#define NWG 256
#define NTH 512
#define WPG 128            // wgs per group
#define FLAG_STRIDE 32u    // one flag per 128-B LLC line

// History half-slots per group, write-once, FRAGMENT-MAJOR:
// shorts offset (rb,kk,lane,j) = ((rb*32+kk)*64+lane)*8+j holds
// h[g*32 + rb*16 + (lane&15)][kk*32 + (lane>>4)*8 + j].
#define HS_SHORTS 32768u                        // 64 KB half-slot
#define GSTRIDE_SH (129u*HS_SHORTS)             // shorts per group hist
#define WS_FLAGS_S 0u                           // 32 KB: startup flags (256 lines)
#define WS_FLAGS_G 32768u                       // 32 KB: per-group arrival flags
#define WS_DUMP    65536u                       // 4 KB: warm-accumulator dump (never hit)
#define WS_H0      131072u
#define WS_H1      (WS_H0 + 2u*129u*65536u)     // +16,908,288
#define WS_CNT     (WS_H1 + 2u*129u*65536u)
#define WS_XS0     (WS_CNT + 4u*NB*NV)
#define WS_NEEDED  (WS_XS0 + 2u*NM*NE)

typedef __attribute__((ext_vector_type(8))) short bf16x8;
typedef __attribute__((ext_vector_type(4))) float f32x4;

#define SCOPE_AG  __HIP_MEMORY_SCOPE_AGENT

__device__ __forceinline__ unsigned short f2bf(float f) {
  unsigned u = __float_as_uint(f);
  u += 0x7FFFu + ((u >> 16) & 1u);   // round-nearest-even
  return (unsigned short)(u >> 16);
}
__device__ __forceinline__ float sigmoidf_(float x) {
  return 1.0f / (1.0f + expf(-x));
}
__device__ __forceinline__ bf16x8 pack8(float4 a, float4 b) {
  bf16x8 v;
  v[0]=(short)f2bf(a.x); v[1]=(short)f2bf(a.y); v[2]=(short)f2bf(a.z); v[3]=(short)f2bf(a.w);
  v[4]=(short)f2bf(b.x); v[5]=(short)f2bf(b.y); v[6]=(short)f2bf(b.z); v[7]=(short)f2bf(b.w);
  return v;
}

#define MFMA(a,b,c) __builtin_amdgcn_mfma_f32_16x16x32_bf16((a),(b),(c),0,0,0)

__global__ void __launch_bounds__(NTH, 2)
lstm_all(const int* __restrict__ x, const float* __restrict__ emb,
         const float* __restrict__ w_ih0, const float* __restrict__ w_hh0,
         const float* __restrict__ b_ih0, const float* __restrict__ b_hh0,
         const float* __restrict__ w_ih1, const float* __restrict__ w_hh1,
         const float* __restrict__ b_ih1, const float* __restrict__ b_hh1,
         const float* __restrict__ fc_w, const float* __restrict__ fc_b,
         float* __restrict__ out, unsigned char* __restrict__ wsb)
{
  // LDS ~141 KB: weight slices in MFMA-fragment order [(ct)][kk][lane][8]
  __shared__ unsigned short sWih1[2*32*64*8];   // 64 KB: w_ih1 ct0+ct1
  __shared__ unsigned short sWhh0c1[32*64*8];   // 32 KB: w_hh0 ct1
  __shared__ unsigned short sWhh1c1[32*64*8];   // 32 KB: w_hh1 ct1
  __shared__ float sG0[32][32], sG1a[32][32], sG1b[32][32], sGih[32][32];
  __shared__ float sB0[32], sB1[32];

  const int wg  = blockIdx.x;
  const int tid = threadIdx.x;
  const int wave = tid >> 6, lane = tid & 63;
  const int lr = lane & 15, lq = lane >> 4;
  const int g  = wg >> 7;          // batch group
  const int wgl = wg & 127;        // wg within group (unit base = wgl*8)

  unsigned* flagsS = (unsigned*)(wsb + WS_FLAGS_S);
  unsigned* gf     = (unsigned*)(wsb + WS_FLAGS_G) + (unsigned)g*WPG*FLAG_STRIDE;
  unsigned short* h0g = (unsigned short*)(wsb + WS_H0) + (size_t)g*GSTRIDE_SH;
  unsigned short* h1g = (unsigned short*)(wsb + WS_H1) + (size_t)g*GSTRIDE_SH;
  unsigned* counts = (unsigned*)(wsb + WS_CNT);
  unsigned short* xs0 = (unsigned short*)(wsb + WS_XS0);

  // ---- breg: step-invariant B-fragments (ct0 of the wave's weight matrix) ----
  // w2/w3: w_hh0 ct0; w0/w1: w_hh1 ct0; w4/w5: w_ih0 ct0(kk<16)+ct1(kk>=16).
  bf16x8 breg[32];
  {
    const int ggr0 = (lr >> 3)*NH + wgl*8 + (lr & 7);          // col c = lr
    const int ggr1 = (2 + (lr >> 3))*NH + wgl*8 + (lr & 7);    // col c = 16+lr
    if (wave == 2 || wave == 3) {
      const float* src = w_hh0 + (size_t)ggr0*NH + lq*8;
      #pragma unroll
      for (int kk = 0; kk < 32; ++kk)
        breg[kk] = pack8(*(const float4*)(src + kk*32), *(const float4*)(src + kk*32 + 4));
    } else if (wave == 0 || wave == 1) {
      const float* src = w_hh1 + (size_t)ggr0*NH + lq*8;
      #pragma unroll
      for (int kk = 0; kk < 32; ++kk)
        breg[kk] = pack8(*(const float4*)(src + kk*32), *(const float4*)(src + kk*32 + 4));
    } else if (wave == 4 || wave == 5) {
      const float* s0 = w_ih0 + (size_t)ggr0*NE + lq*8;
      const float* s1 = w_ih0 + (size_t)ggr1*NE + lq*8;
      #pragma unroll
      for (int kk = 0; kk < 16; ++kk) {
        breg[kk]    = pack8(*(const float4*)(s0 + kk*32), *(const float4*)(s0 + kk*32 + 4));
        breg[16+kk] = pack8(*(const float4*)(s1 + kk*32), *(const float4*)(s1 + kk*32 + 4));
      }
    }
  }

  // ---- gather embeddings -> xs0 (bf16, per-group fragment-major), sc1 ----
  for (int i = wg*NTH + tid; i < NM*(NE/8); i += NWG*NTH) {
    int m = i >> 6;
    int e8 = (i & 63) << 3;
    int t = m >> 6, b = m & 63;
    int tok = x[b*NT + t];
    const float* s = emb + (size_t)tok*NE + e8;
    union { bf16x8 v8; unsigned long long u[2]; } u;
    u.v8 = pack8(*(const float4*)s, *(const float4*)(s + 4));
    int gg = b >> 5, bb = b & 31;
    size_t off = ((size_t)((gg*NT + t)*2 + (bb >> 4)))*8192
               + ((size_t)((e8 >> 5)*64 + ((e8 >> 3) & 3)*16 + (bb & 15)))*8;
    unsigned long long* dst = (unsigned long long*)(xs0 + off);
    __hip_atomic_store(dst,   u.u[0], __ATOMIC_RELAXED, SCOPE_AG);
    __hip_atomic_store(dst+1, u.u[1], __ATOMIC_RELAXED, SCOPE_AG);
  }

  // ---- weight slices -> LDS in fragment order ----
  for (int i = tid; i < 2*32*64; i += NTH) {        // sWih1 ct0+ct1
    int ct = i >> 11, kk = (i >> 6) & 31, l = i & 63;
    int glr = l & 15, glq = l >> 4;
    int c = ct*16 + glr;
    int ggr = (c >> 3)*NH + wgl*8 + (c & 7);
    const float* p = w_ih1 + (size_t)ggr*NH + kk*32 + glq*8;
    ((bf16x8*)sWih1)[i] = pack8(*(const float4*)p, *(const float4*)(p + 4));
  }
  for (int i = tid; i < 32*64; i += NTH) {          // sWhh0c1 / sWhh1c1
    int kk = i >> 6, l = i & 63;
    int glr = l & 15, glq = l >> 4;
    int ggr = (2 + (glr >> 3))*NH + wgl*8 + (glr & 7);   // col c = 16+glr
    const float* p0 = w_hh0 + (size_t)ggr*NH + kk*32 + glq*8;
    const float* p1 = w_hh1 + (size_t)ggr*NH + kk*32 + glq*8;
    ((bf16x8*)sWhh0c1)[i] = pack8(*(const float4*)p0, *(const float4*)(p0 + 4));
    ((bf16x8*)sWhh1c1)[i] = pack8(*(const float4*)p1, *(const float4*)(p1 + 4));
  }
  if (tid < 32) {
    int g2 = (tid >> 3)*NH + wgl*8 + (tid & 7);
    sB0[tid] = b_ih0[g2] + b_hh0[g2];
    sB1[tid] = b_ih1[g2] + b_hh1[g2];
  }
  // ---- token histogram ----
  {
    int i = wg*NTH + tid;
    if (i < NB*NT) {
      int b = i >> 7;
      atomicAdd(&counts[(size_t)b*NV + x[i]], 1u);
    }
  }
  // ---- startup: GLOBAL barrier (gather written by all wgs) ----
  __syncthreads();
  if (tid == 0)
    __hip_atomic_store(&flagsS[(unsigned)wg * FLAG_STRIDE], 1u, __ATOMIC_RELAXED, SCOPE_AG);
  if (tid < NWG) {
    while (__hip_atomic_load(&flagsS[(unsigned)tid * FLAG_STRIDE], __ATOMIC_RELAXED, SCOPE_AG) < 1u)
      __builtin_amdgcn_s_sleep(8);
  }
  __syncthreads();

  // ---- scan: 129 steps, 3 syncthreads/step, publish fused into cells ----
  // MFMA phase: w2/w3 (rb=w-2): A=hist0[t] -> a0ct0(breg) a0ct1 a1ct0 a1ct1(LDS)
  //             w0/w1 (rb=w):   A=hist1[t-1] -> a2ct0(breg) a2ct1(LDS)
  //             w4/w5 (rb=w-4): A=xs[t] -> ai ct0/ct1 (breg)
  //             w6/w7: fc_w LLC-warming (32 B/lane/step)
  // cells: tid<256 layer0 t; tid>=256 layer1 t-1 — each wave shfl-packs its
  //        8 batch rows (8 units = 16 contiguous B fragment-major) and
  //        lane&7==0 stores 2x8 B sc1 directly. No LDS staging, no w6/w7 hop.
  float c_reg = 0.f;
  unsigned warmacc = 0;
  const int cbb = (tid & 255) >> 3, cu8 = tid & 7;
  // 16-B publish chunk (shorts offset) for this thread's batch row cbb:
  const size_t pub16 = ((size_t)(((cbb >> 4)*32 + (wgl >> 2))*64 + (wgl & 3)*16 + (cbb & 15)))*8;
  for (int t = 0; t <= NT; ++t) {
    if (wave == 2 || wave == 3) {
      const int rb = wave - 2;
      const unsigned short* A = h0g + (size_t)t*HS_SHORTS + rb*16384 + lane*8;
      f32x4 a00 = {0.f,0.f,0.f,0.f}, a01 = {0.f,0.f,0.f,0.f};
      f32x4 a10 = {0.f,0.f,0.f,0.f}, a11 = {0.f,0.f,0.f,0.f};
      #pragma unroll
      for (int kk = 0; kk < 32; ++kk) {
        bf16x8 af = *(const bf16x8*)(A + kk*512);
        a00 = MFMA(af, breg[kk], a00);
        a01 = MFMA(af, ((const bf16x8*)sWhh0c1)[kk*64 + lane], a01);
        a10 = MFMA(af, ((const bf16x8*)sWih1)[kk*64 + lane], a10);
        a11 = MFMA(af, ((const bf16x8*)sWih1)[(32+kk)*64 + lane], a11);
      }
      #pragma unroll
      for (int r = 0; r < 4; ++r) {
        int row = rb*16 + lq*4 + r;
        sG0 [row][lr]    = a00[r];
        sG0 [row][16+lr] = a01[r];
        sG1a[row][lr]    = a10[r];
        sG1a[row][16+lr] = a11[r];
      }
    } else if (wave == 0 || wave == 1) {
      if (t >= 1) {
        const int rb = wave;
        const unsigned short* A = h1g + (size_t)(t-1)*HS_SHORTS + rb*16384 + lane*8;
        f32x4 a20 = {0.f,0.f,0.f,0.f}, a21 = {0.f,0.f,0.f,0.f};
        #pragma unroll
        for (int kk = 0; kk < 32; ++kk) {
          bf16x8 af = *(const bf16x8*)(A + kk*512);
          a20 = MFMA(af, breg[kk], a20);
          a21 = MFMA(af, ((const bf16x8*)sWhh1c1)[kk*64 + lane], a21);
        }
        #pragma unroll
        for (int r = 0; r < 4; ++r) {
          int row = rb*16 + lq*4 + r;
          sG1b[row][lr]    = a20[r];
          sG1b[row][16+lr] = a21[r];
        }
      }
    } else if (wave == 4 || wave == 5) {
      if (t < NT) {
        const int rb = wave - 4;
        const unsigned short* A = xs0 + ((size_t)((g*NT + t)*2 + rb))*8192 + lane*8;
        f32x4 ai0 = {0.f,0.f,0.f,0.f}, ai1 = {0.f,0.f,0.f,0.f};
        #pragma unroll
        for (int kk = 0; kk < 16; ++kk) {
          bf16x8 af = *(const bf16x8*)(A + kk*512);
          ai0 = MFMA(af, breg[kk], ai0);
          ai1 = MFMA(af, breg[16+kk], ai1);
        }
        #pragma unroll
        for (int r = 0; r < 4; ++r) {
          int row = rb*16 + lq*4 + r;
          sGih[row][lr]    = ai0[r];
          sGih[row][16+lr] = ai1[r];
        }
      }
    } else {
      // w6/w7: warm fc_w into LLC (1 MB/step chip-wide; 131 MB over 129 steps)
      size_t c = ((size_t)(t*2 + (wave-6))*NWG + wg)*64 + lane;
      if (c*8 + 8 <= (size_t)NV*NH) {
        float4 wv0 = *(const float4*)(fc_w + c*8);
        float4 wv1 = *(const float4*)(fc_w + c*8 + 4);
        warmacc ^= __float_as_uint(wv0.x) ^ __float_as_uint(wv0.w)
                 ^ __float_as_uint(wv1.x) ^ __float_as_uint(wv1.w);
      }
    }
    __syncthreads();
    // ---- cells + fused publish ----
    if (tid < 256) {
      if (t < NT) {
        float gi = sG0[cbb][cu8]    + sGih[cbb][cu8]    + sB0[cu8];
        float gf = sG0[cbb][8+cu8]  + sGih[cbb][8+cu8]  + sB0[8+cu8];
        float gg = sG0[cbb][16+cu8] + sGih[cbb][16+cu8] + sB0[16+cu8];
        float go = sG0[cbb][24+cu8] + sGih[cbb][24+cu8] + sB0[24+cu8];
        float ii = sigmoidf_(gi), ff = sigmoidf_(gf), gv = tanhf(gg), oo = sigmoidf_(go);
        c_reg = ff*c_reg + ii*gv;
        unsigned hb = f2bf(oo * tanhf(c_reg));
        unsigned p0 = hb | (__shfl_down((int)hb, 1) << 16);
        unsigned w1 = (unsigned)__shfl_down((int)p0, 2);
        unsigned w2 = (unsigned)__shfl_down((int)p0, 4);
        unsigned w3 = (unsigned)__shfl_down((int)w1, 4);
        if (cu8 == 0) {
          unsigned long long* dst =
            (unsigned long long*)(h0g + (size_t)(t+1)*HS_SHORTS + pub16);
          __hip_atomic_store(dst,   (unsigned long long)p0 | ((unsigned long long)w1 << 32),
                             __ATOMIC_RELAXED, SCOPE_AG);
          __hip_atomic_store(dst+1, (unsigned long long)w2 | ((unsigned long long)w3 << 32),
                             __ATOMIC_RELAXED, SCOPE_AG);
        }
      }
    } else {
      if (t >= 1) {
        float gi = sG1a[cbb][cu8]    + sG1b[cbb][cu8]    + sB1[cu8];
        float gf = sG1a[cbb][8+cu8]  + sG1b[cbb][8+cu8]  + sB1[8+cu8];
        float gg = sG1a[cbb][16+cu8] + sG1b[cbb][16+cu8] + sB1[16+cu8];
        float go = sG1a[cbb][24+cu8] + sG1b[cbb][24+cu8] + sB1[24+cu8];
        float ii = sigmoidf_(gi), ff = sigmoidf_(gf), gv = tanhf(gg), oo = sigmoidf_(go);
        c_reg = ff*c_reg + ii*gv;
        unsigned hb = f2bf(oo * tanhf(c_reg));
        unsigned p0 = hb | (__shfl_down((int)hb, 1) << 16);
        unsigned w1 = (unsigned)__shfl_down((int)p0, 2);
        unsigned w2 = (unsigned)__shfl_down((int)p0, 4);
        unsigned w3 = (unsigned)__shfl_down((int)w1, 4);
        if (cu8 == 0) {
          unsigned long long* dst =
            (unsigned long long*)(h1g + (size_t)t*HS_SHORTS + pub16);
          __hip_atomic_store(dst,   (unsigned long long)p0 | ((unsigned long long)w1 << 32),
                             __ATOMIC_RELAXED, SCOPE_AG);
          __hip_atomic_store(dst+1, (unsigned long long)w2 | ((unsigned long long)w3 << 32),
                             __ATOMIC_RELAXED, SCOPE_AG);
        }
      }
    }
    // ---- per-group barrier: drain publishes, flag, 128 parallel pollers ----
    __syncthreads();
    if (tid == 0)
      __hip_atomic_store(&gf[(unsigned)wgl * FLAG_STRIDE], (unsigned)(t+1),
                         __ATOMIC_RELAXED, SCOPE_AG);
    if (tid < WPG) {
      while (__hip_atomic_load(&gf[(unsigned)tid * FLAG_STRIDE],
                               __ATOMIC_RELAXED, SCOPE_AG) < (unsigned)(t+1))
        __builtin_amdgcn_s_sleep(1);
    }
    __syncthreads();
  }

  // ---- FC + repetition penalty (group's h1[127] = hist1 slot 128, LLC-warm fc_w) ----
  {
    const unsigned short* ab = h1g + (size_t)128*HS_SHORTS + lane*8;
    for (int tile = wgl*8 + wave; tile < NV/16; tile += WPG*8) {
      int c0 = tile*16;
      const float* wb = fc_w + (size_t)(c0 + lr)*NH + lq*8;
      f32x4 acc0 = {0.f,0.f,0.f,0.f}, acc1 = {0.f,0.f,0.f,0.f};
      #pragma unroll 4
      for (int kk = 0; kk < 32; ++kk) {
        bf16x8 bfv = pack8(*(const float4*)(wb + kk*32), *(const float4*)(wb + kk*32 + 4));
        acc0 = MFMA(*(const bf16x8*)(ab + kk*512),         bfv, acc0);
        acc1 = MFMA(*(const bf16x8*)(ab + 16384 + kk*512), bfv, acc1);
      }
      int c = c0 + lr;
      float fb = fc_b[c];
      #pragma unroll
      for (int r = 0; r < 4; ++r) {
        int b0 = g*32 + lq*4 + r;          // rb = 0
        int b1 = b0 + 16;                  // rb = 1
        unsigned cnt0 = counts[(size_t)b0*NV + c];
        unsigned cnt1 = counts[(size_t)b1*NV + c];
        out[(size_t)b0*NV + c] = (acc0[r] + fb) * exp2f(-0.26303440583379378f * (float)cnt0);
        out[(size_t)b1*NV + c] = (acc1[r] + fb) * exp2f(-0.26303440583379378f * (float)cnt1);
      }
    }
  }
  // keep warm-loads alive (condition is data-dependent; essentially never fires)
  if (warmacc == 0xDEADBEEFu)
    ((volatile unsigned*)(wsb + WS_DUMP))[lane] = warmacc;
}

extern "C" void kernel_launch(void* const* d_in, const int* in_sizes, int n_in,
                              void* d_out, int out_size, void* d_ws, size_t ws_size,
                              hipStream_t stream) {
  const int*   x     = (const int*)  d_in[0];
  const float* emb   = (const float*)d_in[1];
  const float* w_ih0 = (const float*)d_in[2];
  const float* w_hh0 = (const float*)d_in[3];
  const float* b_ih0 = (const float*)d_in[4];
  const float* b_hh0 = (const float*)d_in[5];
  const float* w_ih1 = (const float*)d_in[6];
  const float* w_hh1 = (const float*)d_in[7];
  const float* b_ih1 = (const float*)d_in[8];
  const float* b_hh1 = (const float*)d_in[9];
  const float* fc_w  = (const float*)d_in[10];
  const float* fc_b  = (const float*)d_in[11];
  if (ws_size < WS_NEEDED) return;
  unsigned char* ws = (unsigned char*)d_ws;
  (void)hipMemsetAsync(ws, 0, WS_H0, stream);                          // flags + dump
  (void)hipMemsetAsync(ws + WS_H0, 0, 65536, stream);                  // hist0 g0 slot 0
  (void)hipMemsetAsync(ws + WS_H0 + 129u*65536u, 0, 65536, stream);    // hist0 g1 slot 0
  (void)hipMemsetAsync(ws + WS_H1, 0, 65536, stream);                  // hist1 g0 slot 0
  (void)hipMemsetAsync(ws + WS_H1 + 129u*65536u, 0, 65536, stream);    // hist1 g1 slot 0
  (void)hipMemsetAsync(ws + WS_CNT, 0, 4u*NB*NV, stream);              // token histogram
  hipLaunchKernelGGL(lstm_all, dim3(NWG), dim3(NTH), 0, stream,
                     x, emb, w_ih0, w_hh0, b_ih0, b_hh0,
                     w_ih1, w_hh1, b_ih1, b_hh1, fc_w, fc_b,
                     (float*)d_out, (unsigned char*)d_ws);
}